// Round 1
// baseline (615.590 us; speedup 1.0000x reference)
//
#include <hip/hip_runtime.h>
#include <cfloat>

typedef _Float16 half8  __attribute__((ext_vector_type(8)));
typedef _Float16 half4v __attribute__((ext_vector_type(4)));
typedef short    bf16x8 __attribute__((ext_vector_type(8)));
typedef short    bf16x4 __attribute__((ext_vector_type(4)));
typedef float    floatx4 __attribute__((ext_vector_type(4)));

#define NBATCH 16
#define NSEQ   2048
#define ND     512
#define NC     8192
#define NTOK   (NBATCH * NSEQ)   // 32768
#define NCT    (NC / 128)        // 64 code tiles (tMin granularity, unchanged)
#define KSTEPS (ND / 32)         // 16
#define SEGY   8                 // rescore segment stride
#define MARGIN 0.15f             // bf16 score err sigma ~5e-3, max ~0.022: 28-sigma safe

#define XSCALE 8.0f
#define ESCALE 64.0f
// exact rescore: acc = sum((8x)*(64e)) = 512*xy ; score = e2 - acc/256
#define SCORE_SCALE (2.0f / (XSCALE * ESCALE)) // 1/256

typedef const void __attribute__((address_space(1)))* gp_t;
typedef void       __attribute__((address_space(3)))* lp_t;
__device__ __forceinline__ void cp16(lp_t l, gp_t g) {
  // async global->LDS DMA, 16B/lane, LDS dst = wave-uniform base + lane*16
  __builtin_amdgcn_global_load_lds(g, l, 16, 0, 0);
}

__device__ __forceinline__ short f2bf(float v) {   // RNE fp32->bf16
  unsigned u = __float_as_uint(v);
  return (short)((u + 0x7FFFu + ((u >> 16) & 1u)) >> 16);
}

// ---------------- prep: embed -> bf16 eb + scaled f16 split eh/el ----------------
__global__ __launch_bounds__(256) void prep_embed(const float* __restrict__ embed,
                                                  short* __restrict__ eb,
                                                  _Float16* __restrict__ eh,
                                                  _Float16* __restrict__ el) {
  int idx = blockIdx.x * 256 + threadIdx.x;
  int stride = gridDim.x * 256;
  for (int i = idx; i < NC * ND / 4; i += stride) {
    float4 v = ((const float4*)embed)[i];
    float vs[4] = {v.x, v.y, v.z, v.w};
    bf16x4 bv; half4v h, l;
#pragma unroll
    for (int q = 0; q < 4; ++q) {
      bv[q] = f2bf(vs[q]);
      float sv = ESCALE * vs[q];
      _Float16 hh = (_Float16)sv;
      h[q] = hh;
      l[q] = (_Float16)(sv - (float)hh);
    }
    ((bf16x4*)eb)[i] = bv;
    ((half4v*)eh)[i] = h;
    ((half4v*)el)[i] = l;
  }
}

// ---------------- prep: x -> bf16 xb ----------------
__global__ __launch_bounds__(256) void prep_xb(const float* __restrict__ x,
                                               short* __restrict__ xb) {
  int idx = blockIdx.x * 256 + threadIdx.x;
  int stride = gridDim.x * 256;
  for (int i = idx; i < NTOK * ND / 8; i += stride) {
    float4 a = ((const float4*)x)[2 * i];
    float4 b = ((const float4*)x)[2 * i + 1];
    float vs[8] = {a.x, a.y, a.z, a.w, b.x, b.y, b.z, b.w};
    bf16x8 o;
#pragma unroll
    for (int q = 0; q < 8; ++q) o[q] = f2bf(vs[q]);
    ((bf16x8*)xb)[i] = o;
  }
}

// ---------------- prep: e2[c] = sum_d embed[c][d]^2 ----------------
__global__ __launch_bounds__(256) void prep_e2(const float* __restrict__ embed,
                                               float* __restrict__ e2) {
  int wave = threadIdx.x >> 6, lane = threadIdx.x & 63;
  int c = blockIdx.x * 4 + wave;
  const float* row = embed + (size_t)c * ND;
  float s = 0.f;
  for (int k = lane; k < ND; k += 64) { float v = row[k]; s = fmaf(v, v, s); }
  for (int off = 32; off > 0; off >>= 1) s += __shfl_down(s, off, 64);
  if (lane == 0) e2[c] = s;
}

// ---------------- init keys + counters ----------------
__global__ __launch_bounds__(256) void vq_init(unsigned long long* __restrict__ pKey,
                                               int* __restrict__ cnt) {
  int i = blockIdx.x * 256 + threadIdx.x;
  pKey[i] = ~0ULL;
  if (i < NCT) cnt[i] = 0;
}

// ---------------- pass 1: bf16 GEMM -> per-(token, 128-code-tile) min ----------------
// R7: 256x256 tile, 8 waves (2Mx4N, 128x64 per wave), BK=32, 4-deep LDS ring
// (4 x 32 KiB), phase-split schedule with counted vmcnt (T3+T4) + setprio (T5).
// Tile kt+3 is DMA-staged while computing kt into the buffer last read at kt-1;
// K-tile boundary waits vmcnt(8) (= 2 tiles in flight), draining 8->4->0 at the
// tail -- never a full vmcnt(0) drain in steady state (the m97-structure stall).
// XOR-swizzled LDS (granule (r,cl) holds source granule cl^((r>>1)&3)):
// conflict-free ds_read_b128, DMA-linear writes via pre-swizzled global source.
// Accumulation order per (token,code) identical to R5/R6: scores bitwise same.
__global__ __launch_bounds__(512, 2) void vq_approx(
    const short* __restrict__ xb, const int* __restrict__ len,
    const short* __restrict__ eb, const float* __restrict__ e2g,
    float* __restrict__ tMin) {
  __shared__ short sA[4][256 * 32];   // 64 KiB: X tiles, 4-deep ring
  __shared__ short sB[4][256 * 32];   // 64 KiB: E tiles

  // 256-block super-tiles: 8 M-tiles x 32 N-tiles share xb slice + full eb (L2/L3)
  const int gid = blockIdx.x;
  const int mt = (gid >> 8) * 8 + (gid & 7);
  const int nt = (gid & 255) >> 3;
  const int b = mt >> 3, s0 = (mt & 7) * 256;
  if (s0 >= len[b]) return;
  const int row0 = mt * 256, code0 = nt * 256;

  const int tid = threadIdx.x;
  const int wave = tid >> 6, lane = tid & 63;
  const int quad = lane >> 4, lid = lane & 15;
  const int wm = wave >> 2, wn = wave & 3;    // 2 x 4 wave grid

  // staging: thread covers (row tid>>2, granule tid&3) of a 128-row half;
  // source granule pre-swizzled so LDS holds (r,cl) <- src cl^((r>>1)&3)
  const int r0s = tid >> 2;
  const int csrc = (tid & 3) ^ ((tid >> 3) & 3);
  const int ldsw = wave * 512;                 // wave-uniform LDS base (shorts)

  const short* pA0 = xb + (size_t)(row0 + r0s) * ND + csrc * 8;
  const short* pB0 = eb + (size_t)(code0 + r0s) * ND + csrc * 8;

  const int cswz = quad ^ ((lid >> 1) & 3);
  int aoff[8], boff[4];
#pragma unroll
  for (int i = 0; i < 8; ++i) aoff[i] = (wm * 128 + i * 16 + lid) * 32 + cswz * 8;
#pragma unroll
  for (int j = 0; j < 4; ++j) boff[j] = (wn * 64 + j * 16 + lid) * 32 + cswz * 8;

  floatx4 acc[8][4];
#pragma unroll
  for (int i = 0; i < 8; ++i)
#pragma unroll
    for (int j = 0; j < 4; ++j) acc[i][j] = (floatx4){0.f, 0.f, 0.f, 0.f};

#define STAGE_A(bufi, kt) do { \
    cp16((lp_t)&sA[bufi][ldsw],        (gp_t)(pA0 + (kt) * 32)); \
    cp16((lp_t)&sA[bufi][4096 + ldsw], (gp_t)(pA0 + 128 * ND + (kt) * 32)); } while (0)
#define STAGE_B(bufi, kt) do { \
    cp16((lp_t)&sB[bufi][ldsw],        (gp_t)(pB0 + (kt) * 32)); \
    cp16((lp_t)&sB[bufi][4096 + ldsw], (gp_t)(pB0 + 128 * ND + (kt) * 32)); } while (0)

  // prologue: stage tiles 0..2 (12 issues/wave), land tile 0, keep 8 in flight
  STAGE_A(0, 0); STAGE_B(0, 0);
  STAGE_A(1, 1); STAGE_B(1, 1);
  STAGE_A(2, 2); STAGE_B(2, 2);
  asm volatile("s_waitcnt vmcnt(8)" ::: "memory");
  __builtin_amdgcn_s_barrier();

#pragma unroll
  for (int kt = 0; kt < KSTEPS; ++kt) {
    const int buf = kt & 3;
    const short* A = sA[buf];
    const short* B = sB[buf];
    bf16x8 av[4], bv[4];
    // ---- phase 1: frags m0-3 x n0-3; stage A-halves of kt+3 ----
#pragma unroll
    for (int i = 0; i < 4; ++i) av[i] = *(const bf16x8*)&A[aoff[i]];
#pragma unroll
    for (int j = 0; j < 4; ++j) bv[j] = *(const bf16x8*)&B[boff[j]];
    if (kt + 3 < KSTEPS) STAGE_A((kt + 3) & 3, kt + 3);
    __builtin_amdgcn_s_barrier();
    asm volatile("s_waitcnt lgkmcnt(0)" ::: "memory");
    __builtin_amdgcn_s_setprio(1);
#pragma unroll
    for (int i = 0; i < 4; ++i)
#pragma unroll
      for (int j = 0; j < 4; ++j)
        acc[i][j] = __builtin_amdgcn_mfma_f32_16x16x32_bf16(av[i], bv[j], acc[i][j], 0, 0, 0);
    __builtin_amdgcn_s_setprio(0);
    __builtin_amdgcn_s_barrier();
    // ---- phase 2: frags m4-7 x n0-3 (reuse bv); stage B-halves of kt+3 ----
#pragma unroll
    for (int i = 0; i < 4; ++i) av[i] = *(const bf16x8*)&A[aoff[4 + i]];
    if (kt + 3 < KSTEPS) STAGE_B((kt + 3) & 3, kt + 3);
    __builtin_amdgcn_s_barrier();
    asm volatile("s_waitcnt lgkmcnt(0)" ::: "memory");
    __builtin_amdgcn_s_setprio(1);
#pragma unroll
    for (int i = 0; i < 4; ++i)
#pragma unroll
      for (int j = 0; j < 4; ++j)
        acc[4 + i][j] = __builtin_amdgcn_mfma_f32_16x16x32_bf16(av[i], bv[j], acc[4 + i][j], 0, 0, 0);
    __builtin_amdgcn_s_setprio(0);
    // K-tile boundary: counted wait -- next tile landed, <=2 tiles in flight
    if (kt < KSTEPS - 3)       { asm volatile("s_waitcnt vmcnt(8)" ::: "memory"); }
    else if (kt == KSTEPS - 3) { asm volatile("s_waitcnt vmcnt(4)" ::: "memory"); }
    else if (kt == KSTEPS - 2) { asm volatile("s_waitcnt vmcnt(0)" ::: "memory"); }
    __builtin_amdgcn_s_barrier();
  }
#undef STAGE_A
#undef STAGE_B

  // epilogue: per-token min per 64-code wave column, combine pairs -> 128-code tMin
  float e2v[4];
#pragma unroll
  for (int j = 0; j < 4; ++j) e2v[j] = e2g[code0 + wn * 64 + j * 16 + lid];

  __syncthreads();                  // all waves done with LDS -> alias scratch
  float* sc = (float*)&sA[0][0];    // [256][4]
#pragma unroll
  for (int i = 0; i < 8; ++i) {
#pragma unroll
    for (int reg = 0; reg < 4; ++reg) {
      float best = fmaf(-2.0f, acc[i][0][reg], e2v[0]);
#pragma unroll
      for (int j = 1; j < 4; ++j)
        best = fminf(best, fmaf(-2.0f, acc[i][j][reg], e2v[j]));
#pragma unroll
      for (int m = 1; m < 16; m <<= 1) best = fminf(best, __shfl_xor(best, m, 64));
      if (lid == 0) sc[(wm * 128 + i * 16 + quad * 4 + reg) * 4 + wn] = best;
    }
  }
  __syncthreads();
  {
    int rrow = tid & 255, pr = tid >> 8;
    float v = fminf(sc[rrow * 4 + pr * 2], sc[rrow * 4 + pr * 2 + 1]);
    tMin[(size_t)(row0 + rrow) * NCT + nt * 2 + pr] = v;
  }
}

// ---------------- pass 2: select candidate tiles per token ----------------
__global__ __launch_bounds__(256) void vq_select(
    const int* __restrict__ len, const float* __restrict__ tMin,
    int* __restrict__ list, int* __restrict__ cnt) {
  int wave = threadIdx.x >> 6, lane = threadIdx.x & 63;
  int t = blockIdx.x * 4 + wave;
  int b = t >> 11, s = t & (NSEQ - 1);
  if (s >= len[b]) return;   // wave-uniform
  float v = tMin[(size_t)t * NCT + lane];
  float m = v;
#pragma unroll
  for (int d = 1; d < 64; d <<= 1) m = fminf(m, __shfl_xor(m, d, 64));
  if (v <= m + MARGIN) {
    int pos = atomicAdd(&cnt[lane], 1);
    list[lane * NTOK + pos] = t;
  }
}

// ---------------- pass 3: exact 3-product f16 rescore (barrier-free, pipelined) ----
// One block per (code tile j, segment y). Each wave computes a 64x64 quadrant;
// A rows (gathered tokens) and B rows (codes) load global->register; kt loop
// unrolled x2 with ALL 32 loads of the pair issued before convert/MFMA: one
// memory latency per 2 kt instead of a serial per-load chain (blocks run at
// ~1 wave/SIMD, so intra-wave ILP is the only latency hiding available).
// atomicMin on sortable (score,idx) u64 key: order-independent, idempotent.
__global__ __launch_bounds__(256, 1) void vq_rescore(
    const float* __restrict__ x,
    const _Float16* __restrict__ eh, const _Float16* __restrict__ el,
    const float* __restrict__ e2g,
    const int* __restrict__ list, const int* __restrict__ cnt,
    unsigned long long* __restrict__ pKey) {
  const int j = blockIdx.x;
  const int n = cnt[j];
  const int code0 = j * 128;

  const int tid = threadIdx.x, wave = tid >> 6, lane = tid & 63;
  const int quad = lane >> 4, lid = lane & 15;
  const int wr = wave >> 1, wc = wave & 1;

  float e2v[4]; int cjv[4];
#pragma unroll
  for (int jj = 0; jj < 4; ++jj) {
    cjv[jj] = code0 + wc * 64 + jj * 16 + lid;   // B row = C/D col = lane&15
    e2v[jj] = e2g[cjv[jj]];
  }

  for (int seg = blockIdx.y; seg * 128 < n; seg += SEGY) {
    const int base = seg * 128;
    int tok[4];
#pragma unroll
    for (int i = 0; i < 4; ++i)
      tok[i] = list[j * NTOK + min(base + wr * 64 + i * 16 + lid, n - 1)];

    floatx4 acc[4][4];
#pragma unroll
    for (int i = 0; i < 4; ++i)
#pragma unroll
      for (int jj = 0; jj < 4; ++jj) acc[i][jj] = (floatx4){0.f, 0.f, 0.f, 0.f};

    for (int kt = 0; kt < 16; kt += 2) {
      // ---- issue ALL loads for the kt pair (32 instrs in flight) ----
      float4 af[2][4][2];
#pragma unroll
      for (int s = 0; s < 2; ++s)
#pragma unroll
        for (int i = 0; i < 4; ++i) {
          const float* px = x + (size_t)tok[i] * ND + (kt + s) * 32 + quad * 8;
          af[s][i][0] = *(const float4*)px;
          af[s][i][1] = *(const float4*)(px + 4);
        }
      half8 bh[2][4], bl[2][4];
#pragma unroll
      for (int s = 0; s < 2; ++s)
#pragma unroll
        for (int jj = 0; jj < 4; ++jj) {
          const size_t eo = (size_t)cjv[jj] * ND + (kt + s) * 32 + quad * 8;
          bh[s][jj] = *(const half8*)(eh + eo);
          bl[s][jj] = *(const half8*)(el + eo);
        }
      // ---- process sub-steps in order (same arithmetic order as R5/R6) ----
#pragma unroll
      for (int s = 0; s < 2; ++s) {
        half8 ah[4], al[4];
#pragma unroll
        for (int i = 0; i < 4; ++i) {
          float vs[8] = {af[s][i][0].x, af[s][i][0].y, af[s][i][0].z, af[s][i][0].w,
                         af[s][i][1].x, af[s][i][1].y, af[s][i][1].z, af[s][i][1].w};
#pragma unroll
          for (int q = 0; q < 8; ++q) {
            float vv = XSCALE * vs[q];
            _Float16 hh = (_Float16)vv;
            ah[i][q] = hh;
            al[i][q] = (_Float16)(vv - (float)hh);
          }
        }
#pragma unroll
        for (int i = 0; i < 4; ++i)
#pragma unroll
          for (int jj = 0; jj < 4; ++jj) {
            acc[i][jj] = __builtin_amdgcn_mfma_f32_16x16x32_f16(ah[i], bh[s][jj], acc[i][jj], 0, 0, 0);
            acc[i][jj] = __builtin_amdgcn_mfma_f32_16x16x32_f16(ah[i], bl[s][jj], acc[i][jj], 0, 0, 0);
            acc[i][jj] = __builtin_amdgcn_mfma_f32_16x16x32_f16(al[i], bh[s][jj], acc[i][jj], 0, 0, 0);
          }
      }
    }

    // epilogue: per-row argmin over the 128 codes, publish via atomicMin
#pragma unroll
    for (int i = 0; i < 4; ++i) {
#pragma unroll
      for (int reg = 0; reg < 4; ++reg) {
        float best = fmaf(-SCORE_SCALE, acc[i][0][reg], e2v[0]);
        int bidx = cjv[0];
#pragma unroll
        for (int jj = 1; jj < 4; ++jj) {
          float vj = fmaf(-SCORE_SCALE, acc[i][jj][reg], e2v[jj]);
          if (vj < best) { best = vj; bidx = cjv[jj]; }   // strict <: lowest idx on ties
        }
#pragma unroll
        for (int m = 1; m < 16; m <<= 1) {
          float ov = __shfl_xor(best, m, 64);
          int   oi = __shfl_xor(bidx, m, 64);
          if (ov < best || (ov == best && oi < bidx)) { best = ov; bidx = oi; }
        }
        if (lid == 0) {
          int row = wr * 64 + i * 16 + quad * 4 + reg;    // C/D row = quad*4+reg
          int t = list[j * NTOK + min(base + row, n - 1)];
          if (best == 0.0f) best = 0.0f;                  // normalize -0
          unsigned u = __float_as_uint(best);
          u ^= (u >> 31) ? 0xFFFFFFFFu : 0x80000000u;     // sortable fp32
          unsigned long long key = ((unsigned long long)u << 32) | (unsigned)bidx;
          atomicMin(&pKey[t], key);
        }
      }
    }
  }
}

// ---------------- decode key, gather code row, apply mask ----------------
__global__ __launch_bounds__(256) void vq_output(
    const float* __restrict__ embed, const int* __restrict__ len,
    const unsigned long long* __restrict__ pKey,
    float* __restrict__ out) {
  int wave = threadIdx.x >> 6, lane = threadIdx.x & 63;
  int t = blockIdx.x * 4 + wave;
  int b = t >> 11, s = t & (NSEQ - 1);
  float* outq = out + (size_t)t * ND;
  float* outind = out + (size_t)NTOK * ND;
  if (s >= len[b]) {
    float4 z = {0.f, 0.f, 0.f, 0.f};
    *(float4*)&outq[lane * 8]     = z;
    *(float4*)&outq[lane * 8 + 4] = z;
    if (lane == 0) outind[t] = -1.0f;
    return;
  }
  unsigned long long key = pKey[t];
  int bi = (int)(unsigned)(key & 0xFFFFFFFFULL);
  const float* er = embed + (size_t)bi * ND;
  *(float4*)&outq[lane * 8]     = *(const float4*)&er[lane * 8];
  *(float4*)&outq[lane * 8 + 4] = *(const float4*)&er[lane * 8 + 4];
  if (lane == 0) outind[t] = (float)bi;
}

extern "C" void kernel_launch(void* const* d_in, const int* in_sizes, int n_in,
                              void* d_out, int out_size, void* d_ws, size_t ws_size,
                              hipStream_t stream) {
  const float* x     = (const float*)d_in[0];
  const int*   lenp  = (const int*)d_in[1];
  const float* embed = (const float*)d_in[2];
  float* out = (float*)d_out;

  // ws: eb 8M | eh 8M | el 8M | e2 32K | xb 32M | tMin 8M | list 8M | cnt | pKey  ~72.5 MB
  char* w = (char*)d_ws;
  size_t off = 0;
  short*    eb = (short*)(w + off);    off += (size_t)NC * ND * 2;
  _Float16* eh = (_Float16*)(w + off); off += (size_t)NC * ND * 2;
  _Float16* el = (_Float16*)(w + off); off += (size_t)NC * ND * 2;
  float*    e2 = (float*)(w + off);    off += (size_t)NC * 4;
  short*    xb = (short*)(w + off);    off += (size_t)NTOK * ND * 2;
  float*  tMin = (float*)(w + off);    off += (size_t)NTOK * NCT * 4;
  int*    list = (int*)(w + off);      off += (size_t)NCT * NTOK * 4;
  int*     cnt = (int*)(w + off);      off += 256;
  unsigned long long* pKey = (unsigned long long*)(w + off); off += (size_t)NTOK * 8;

  prep_embed<<<1024, 256, 0, stream>>>(embed, eb, eh, el);
  prep_e2<<<NC / 4, 256, 0, stream>>>(embed, e2);
  prep_xb<<<2048, 256, 0, stream>>>(x, xb);
  vq_init<<<NTOK / 256, 256, 0, stream>>>(pKey, cnt);
  vq_approx<<<(NTOK / 256) * (NC / 256), 512, 0, stream>>>(xb, lenp, eb, e2, tMin);
  vq_select<<<NTOK / 4, 256, 0, stream>>>(lenp, tMin, list, cnt);
  vq_rescore<<<dim3(NCT, SEGY), 256, 0, stream>>>(x, eh, el, e2, list, cnt, pKey);
  vq_output<<<NTOK / 4, 256, 0, stream>>>(embed, lenp, pKey, out);
}

// Round 2
// 527.618 us; speedup vs baseline: 1.1667x; 1.1667x over previous
//
#include <hip/hip_runtime.h>
#include <cfloat>

typedef _Float16 half8  __attribute__((ext_vector_type(8)));
typedef _Float16 half4v __attribute__((ext_vector_type(4)));
typedef short    bf16x8 __attribute__((ext_vector_type(8)));
typedef short    bf16x4 __attribute__((ext_vector_type(4)));
typedef float    floatx4 __attribute__((ext_vector_type(4)));

#define NBATCH 16
#define NSEQ   2048
#define ND     512
#define NC     8192
#define NTOK   (NBATCH * NSEQ)   // 32768
#define NTT    (NTOK / 128)      // 256 token tiles
#define NCT    (NC / 128)        // 64 code tiles
#define KSTEPS (ND / 32)         // 16
#define SEGY   8                 // rescore segment stride
#define MARGIN 0.15f             // bf16 score err sigma ~5e-3, max ~0.022: 28-sigma safe

#define XSCALE 8.0f
#define ESCALE 64.0f
// exact rescore: acc = sum((8x)*(64e)) = 512*xy ; score = e2 - acc/256
#define SCORE_SCALE (2.0f / (XSCALE * ESCALE)) // 1/256

typedef const void __attribute__((address_space(1)))* gp_t;
typedef void       __attribute__((address_space(3)))* lp_t;
__device__ __forceinline__ void cp16(lp_t l, gp_t g) {
  // async global->LDS DMA, 16B/lane, LDS dst = wave-uniform base + lane*16
  __builtin_amdgcn_global_load_lds(g, l, 16, 0, 0);
}

__device__ __forceinline__ short f2bf(float v) {   // RNE fp32->bf16
  unsigned u = __float_as_uint(v);
  return (short)((u + 0x7FFFu + ((u >> 16) & 1u)) >> 16);
}

// ---------------- prep: embed -> bf16 eb + scaled f16 split eh/el ----------------
__global__ __launch_bounds__(256) void prep_embed(const float* __restrict__ embed,
                                                  short* __restrict__ eb,
                                                  _Float16* __restrict__ eh,
                                                  _Float16* __restrict__ el) {
  int idx = blockIdx.x * 256 + threadIdx.x;
  int stride = gridDim.x * 256;
  for (int i = idx; i < NC * ND / 4; i += stride) {
    float4 v = ((const float4*)embed)[i];
    float vs[4] = {v.x, v.y, v.z, v.w};
    bf16x4 bv; half4v h, l;
#pragma unroll
    for (int q = 0; q < 4; ++q) {
      bv[q] = f2bf(vs[q]);
      float sv = ESCALE * vs[q];
      _Float16 hh = (_Float16)sv;
      h[q] = hh;
      l[q] = (_Float16)(sv - (float)hh);
    }
    ((bf16x4*)eb)[i] = bv;
    ((half4v*)eh)[i] = h;
    ((half4v*)el)[i] = l;
  }
}

// ---------------- prep: x -> bf16 xb ----------------
__global__ __launch_bounds__(256) void prep_xb(const float* __restrict__ x,
                                               short* __restrict__ xb) {
  int idx = blockIdx.x * 256 + threadIdx.x;
  int stride = gridDim.x * 256;
  for (int i = idx; i < NTOK * ND / 8; i += stride) {
    float4 a = ((const float4*)x)[2 * i];
    float4 b = ((const float4*)x)[2 * i + 1];
    float vs[8] = {a.x, a.y, a.z, a.w, b.x, b.y, b.z, b.w};
    bf16x8 o;
#pragma unroll
    for (int q = 0; q < 8; ++q) o[q] = f2bf(vs[q]);
    ((bf16x8*)xb)[i] = o;
  }
}

// ---------------- prep: e2[c] = sum_d embed[c][d]^2 ----------------
__global__ __launch_bounds__(256) void prep_e2(const float* __restrict__ embed,
                                               float* __restrict__ e2) {
  int wave = threadIdx.x >> 6, lane = threadIdx.x & 63;
  int c = blockIdx.x * 4 + wave;
  const float* row = embed + (size_t)c * ND;
  float s = 0.f;
  for (int k = lane; k < ND; k += 64) { float v = row[k]; s = fmaf(v, v, s); }
  for (int off = 32; off > 0; off >>= 1) s += __shfl_down(s, off, 64);
  if (lane == 0) e2[c] = s;
}

// ---------------- init keys + counters ----------------
__global__ __launch_bounds__(256) void vq_init(unsigned long long* __restrict__ pKey,
                                               int* __restrict__ cnt) {
  int i = blockIdx.x * 256 + threadIdx.x;
  pKey[i] = ~0ULL;
  if (i < NCT) cnt[i] = 0;
}

// ---------------- pass 1: bf16 1-product GEMM -> per-(token, code-tile) min ----------------
// R8: R5's proven 128x128 tile / 256 threads / XOR-swizzled LDS, but the
// double-buffer + per-kt full vmcnt(0) drain + 2 barriers (the m97 structural
// stall, paid 16x serially against L3-latency staging) is replaced by a 3-deep
// LDS ring (48 KiB -> still 3 blocks/CU residency) with ONE barrier per K-step
// and counted vmcnt(4): tile kt+2 is DMA-staged while computing kt, into the
// buffer last read at kt-1 (reads retired before the end-of-(kt-1) barrier).
// vmcnt never drains to 0 until the tail. MFMA order per (token,code) is
// unchanged -> pass-1 scores bitwise identical to R5 (MARGIN semantics safe).
__global__ __launch_bounds__(256) void vq_approx(
    const short* __restrict__ xb, const int* __restrict__ len,
    const short* __restrict__ eb, const float* __restrict__ e2g,
    float* __restrict__ tMin) {
  __shared__ short sXb[3][128 * 32];   // 3 x 8 KiB ring
  __shared__ short sEb[3][128 * 32];   // 3 x 8 KiB ring

  // 8x64 super-tiles: 512 consecutive blocks share 8 X-tiles (L2) + full eb
  const int gid = blockIdx.x;
  const int tt = (gid >> 9) * 8 + (gid & 7);
  const int ct = (gid & 511) >> 3;
  const int b = tt >> 4, s0 = (tt & 15) * 128;
  if (s0 >= len[b]) return;
  const int row0 = tt * 128, code0 = ct * 128;

  const int tid = threadIdx.x, wave = tid >> 6, lane = tid & 63;
  const int quad = lane >> 4, lid = lane & 15;
  const int wr = wave >> 1, wc = wave & 1;

  const int r0 = tid >> 2;
  const int csrc = (tid & 3) ^ ((tid >> 3) & 3);
  const int ldsg0 = (wave * 64) * 8;
  const int ldsg1 = (256 + wave * 64) * 8;

  const int cswz = quad ^ ((lid >> 1) & 3);
  int aoff[4], boff[4];
#pragma unroll
  for (int i = 0; i < 4; ++i) aoff[i] = (wr * 64 + i * 16 + lid) * 32 + cswz * 8;
#pragma unroll
  for (int j = 0; j < 4; ++j) boff[j] = (wc * 64 + j * 16 + lid) * 32 + cswz * 8;

  const short* pxb = xb + (size_t)(row0 + r0) * ND + csrc * 8;
  const short* peb = eb + (size_t)(code0 + r0) * ND + csrc * 8;

  floatx4 acc[4][4];
#pragma unroll
  for (int i = 0; i < 4; ++i)
#pragma unroll
    for (int j = 0; j < 4; ++j) acc[i][j] = (floatx4){0.f, 0.f, 0.f, 0.f};

  // 4 VMEM issues per tile per wave
#define STAGE(bufi, kt) do { \
    cp16((lp_t)&sXb[bufi][ldsg0], (gp_t)(pxb + (kt) * 32)); \
    cp16((lp_t)&sXb[bufi][ldsg1], (gp_t)(pxb + 64 * ND + (kt) * 32)); \
    cp16((lp_t)&sEb[bufi][ldsg0], (gp_t)(peb + (kt) * 32)); \
    cp16((lp_t)&sEb[bufi][ldsg1], (gp_t)(peb + 64 * ND + (kt) * 32)); } while (0)

  // prologue: stage tiles 0,1 (8 issues); land tile 0, keep tile 1 in flight
  STAGE(0, 0);
  STAGE(1, 1);
  asm volatile("s_waitcnt vmcnt(4)" ::: "memory");
  __builtin_amdgcn_s_barrier();

#pragma unroll
  for (int kt = 0; kt < KSTEPS; ++kt) {
    const int buf = kt % 3;
    // stage kt+2 into the buffer read at kt-1 (safe: freed by the kt-1 barrier)
    if (kt + 2 < KSTEPS) STAGE((kt + 2) % 3, kt + 2);
    const short* A = sXb[buf];
    const short* B = sEb[buf];
    bf16x8 av[4], bv[4];
#pragma unroll
    for (int j = 0; j < 4; ++j) bv[j] = *(const bf16x8*)&B[boff[j]];
#pragma unroll
    for (int i = 0; i < 4; ++i) av[i] = *(const bf16x8*)&A[aoff[i]];
    __builtin_amdgcn_s_setprio(1);
#pragma unroll
    for (int i = 0; i < 4; ++i)
#pragma unroll
      for (int j = 0; j < 4; ++j)
        acc[i][j] = __builtin_amdgcn_mfma_f32_16x16x32_bf16(av[i], bv[j], acc[i][j], 0, 0, 0);
    __builtin_amdgcn_s_setprio(0);
    // boundary: counted wait -- tile kt+1 landed, tile kt+2 stays in flight
    if (kt < KSTEPS - 1) {
      if (kt <= KSTEPS - 3) { asm volatile("s_waitcnt vmcnt(4)" ::: "memory"); }
      else                  { asm volatile("s_waitcnt vmcnt(0)" ::: "memory"); }
      __builtin_amdgcn_s_barrier();
    }
  }
#undef STAGE

  // per-token min over this 128-code tile (value only)
  float e2v[4];
#pragma unroll
  for (int j = 0; j < 4; ++j) e2v[j] = e2g[code0 + wc * 64 + j * 16 + lid];

  __syncthreads();                  // all waves done with LDS -> alias scratch
  float* sc = (float*)&sXb[0][0];   // [128][2]
#pragma unroll
  for (int i = 0; i < 4; ++i) {
#pragma unroll
    for (int reg = 0; reg < 4; ++reg) {
      float best = fmaf(-2.0f, acc[i][0][reg], e2v[0]);
#pragma unroll
      for (int j = 1; j < 4; ++j)
        best = fminf(best, fmaf(-2.0f, acc[i][j][reg], e2v[j]));
#pragma unroll
      for (int m = 1; m < 16; m <<= 1) best = fminf(best, __shfl_xor(best, m, 64));
      if (lid == 0) sc[(wr * 64 + i * 16 + quad * 4 + reg) * 2 + wc] = best;
    }
  }
  __syncthreads();
  if (tid < 128)
    tMin[(size_t)(row0 + tid) * NCT + ct] = fminf(sc[tid * 2], sc[tid * 2 + 1]);
}

// ---------------- pass 2: select candidate tiles per token ----------------
__global__ __launch_bounds__(256) void vq_select(
    const int* __restrict__ len, const float* __restrict__ tMin,
    int* __restrict__ list, int* __restrict__ cnt) {
  int wave = threadIdx.x >> 6, lane = threadIdx.x & 63;
  int t = blockIdx.x * 4 + wave;
  int b = t >> 11, s = t & (NSEQ - 1);
  if (s >= len[b]) return;   // wave-uniform
  float v = tMin[(size_t)t * NCT + lane];
  float m = v;
#pragma unroll
  for (int d = 1; d < 64; d <<= 1) m = fminf(m, __shfl_xor(m, d, 64));
  if (v <= m + MARGIN) {
    int pos = atomicAdd(&cnt[lane], 1);
    list[lane * NTOK + pos] = t;
  }
}

// ---------------- pass 3: exact 3-product f16 rescore (barrier-free, pipelined) ----
// One block per (code tile j, segment y). Each wave computes a 64x64 quadrant;
// A rows (gathered tokens) and B rows (codes) load global->register; kt loop
// unrolled x2 with ALL 32 loads of the pair issued before convert/MFMA: one
// memory latency per 2 kt instead of a serial per-load chain (blocks run at
// ~1 wave/SIMD, so intra-wave ILP is the only latency hiding available).
// atomicMin on sortable (score,idx) u64 key: order-independent, idempotent.
__global__ __launch_bounds__(256, 1) void vq_rescore(
    const float* __restrict__ x,
    const _Float16* __restrict__ eh, const _Float16* __restrict__ el,
    const float* __restrict__ e2g,
    const int* __restrict__ list, const int* __restrict__ cnt,
    unsigned long long* __restrict__ pKey) {
  const int j = blockIdx.x;
  const int n = cnt[j];
  const int code0 = j * 128;

  const int tid = threadIdx.x, wave = tid >> 6, lane = tid & 63;
  const int quad = lane >> 4, lid = lane & 15;
  const int wr = wave >> 1, wc = wave & 1;

  float e2v[4]; int cjv[4];
#pragma unroll
  for (int jj = 0; jj < 4; ++jj) {
    cjv[jj] = code0 + wc * 64 + jj * 16 + lid;   // B row = C/D col = lane&15
    e2v[jj] = e2g[cjv[jj]];
  }

  for (int seg = blockIdx.y; seg * 128 < n; seg += SEGY) {
    const int base = seg * 128;
    int tok[4];
#pragma unroll
    for (int i = 0; i < 4; ++i)
      tok[i] = list[j * NTOK + min(base + wr * 64 + i * 16 + lid, n - 1)];

    floatx4 acc[4][4];
#pragma unroll
    for (int i = 0; i < 4; ++i)
#pragma unroll
      for (int jj = 0; jj < 4; ++jj) acc[i][jj] = (floatx4){0.f, 0.f, 0.f, 0.f};

    for (int kt = 0; kt < 16; kt += 2) {
      // ---- issue ALL loads for the kt pair (32 instrs in flight) ----
      float4 af[2][4][2];
#pragma unroll
      for (int s = 0; s < 2; ++s)
#pragma unroll
        for (int i = 0; i < 4; ++i) {
          const float* px = x + (size_t)tok[i] * ND + (kt + s) * 32 + quad * 8;
          af[s][i][0] = *(const float4*)px;
          af[s][i][1] = *(const float4*)(px + 4);
        }
      half8 bh[2][4], bl[2][4];
#pragma unroll
      for (int s = 0; s < 2; ++s)
#pragma unroll
        for (int jj = 0; jj < 4; ++jj) {
          const size_t eo = (size_t)cjv[jj] * ND + (kt + s) * 32 + quad * 8;
          bh[s][jj] = *(const half8*)(eh + eo);
          bl[s][jj] = *(const half8*)(el + eo);
        }
      // ---- process sub-steps in order (same arithmetic order as R5/R6) ----
#pragma unroll
      for (int s = 0; s < 2; ++s) {
        half8 ah[4], al[4];
#pragma unroll
        for (int i = 0; i < 4; ++i) {
          float vs[8] = {af[s][i][0].x, af[s][i][0].y, af[s][i][0].z, af[s][i][0].w,
                         af[s][i][1].x, af[s][i][1].y, af[s][i][1].z, af[s][i][1].w};
#pragma unroll
          for (int q = 0; q < 8; ++q) {
            float vv = XSCALE * vs[q];
            _Float16 hh = (_Float16)vv;
            ah[i][q] = hh;
            al[i][q] = (_Float16)(vv - (float)hh);
          }
        }
#pragma unroll
        for (int i = 0; i < 4; ++i)
#pragma unroll
          for (int jj = 0; jj < 4; ++jj) {
            acc[i][jj] = __builtin_amdgcn_mfma_f32_16x16x32_f16(ah[i], bh[s][jj], acc[i][jj], 0, 0, 0);
            acc[i][jj] = __builtin_amdgcn_mfma_f32_16x16x32_f16(ah[i], bl[s][jj], acc[i][jj], 0, 0, 0);
            acc[i][jj] = __builtin_amdgcn_mfma_f32_16x16x32_f16(al[i], bh[s][jj], acc[i][jj], 0, 0, 0);
          }
      }
    }

    // epilogue: per-row argmin over the 128 codes, publish via atomicMin
#pragma unroll
    for (int i = 0; i < 4; ++i) {
#pragma unroll
      for (int reg = 0; reg < 4; ++reg) {
        float best = fmaf(-SCORE_SCALE, acc[i][0][reg], e2v[0]);
        int bidx = cjv[0];
#pragma unroll
        for (int jj = 1; jj < 4; ++jj) {
          float vj = fmaf(-SCORE_SCALE, acc[i][jj][reg], e2v[jj]);
          if (vj < best) { best = vj; bidx = cjv[jj]; }   // strict <: lowest idx on ties
        }
#pragma unroll
        for (int m = 1; m < 16; m <<= 1) {
          float ov = __shfl_xor(best, m, 64);
          int   oi = __shfl_xor(bidx, m, 64);
          if (ov < best || (ov == best && oi < bidx)) { best = ov; bidx = oi; }
        }
        if (lid == 0) {
          int row = wr * 64 + i * 16 + quad * 4 + reg;    // C/D row = quad*4+reg
          int t = list[j * NTOK + min(base + row, n - 1)];
          if (best == 0.0f) best = 0.0f;                  // normalize -0
          unsigned u = __float_as_uint(best);
          u ^= (u >> 31) ? 0xFFFFFFFFu : 0x80000000u;     // sortable fp32
          unsigned long long key = ((unsigned long long)u << 32) | (unsigned)bidx;
          atomicMin(&pKey[t], key);
        }
      }
    }
  }
}

// ---------------- decode key, gather code row, apply mask ----------------
__global__ __launch_bounds__(256) void vq_output(
    const float* __restrict__ embed, const int* __restrict__ len,
    const unsigned long long* __restrict__ pKey,
    float* __restrict__ out) {
  int wave = threadIdx.x >> 6, lane = threadIdx.x & 63;
  int t = blockIdx.x * 4 + wave;
  int b = t >> 11, s = t & (NSEQ - 1);
  float* outq = out + (size_t)t * ND;
  float* outind = out + (size_t)NTOK * ND;
  if (s >= len[b]) {
    float4 z = {0.f, 0.f, 0.f, 0.f};
    *(float4*)&outq[lane * 8]     = z;
    *(float4*)&outq[lane * 8 + 4] = z;
    if (lane == 0) outind[t] = -1.0f;
    return;
  }
  unsigned long long key = pKey[t];
  int bi = (int)(unsigned)(key & 0xFFFFFFFFULL);
  const float* er = embed + (size_t)bi * ND;
  *(float4*)&outq[lane * 8]     = *(const float4*)&er[lane * 8];
  *(float4*)&outq[lane * 8 + 4] = *(const float4*)&er[lane * 8 + 4];
  if (lane == 0) outind[t] = (float)bi;
}

extern "C" void kernel_launch(void* const* d_in, const int* in_sizes, int n_in,
                              void* d_out, int out_size, void* d_ws, size_t ws_size,
                              hipStream_t stream) {
  const float* x     = (const float*)d_in[0];
  const int*   lenp  = (const int*)d_in[1];
  const float* embed = (const float*)d_in[2];
  float* out = (float*)d_out;

  // ws: eb 8M | eh 8M | el 8M | e2 32K | xb 32M | tMin 8M | list 8M | cnt | pKey  ~72.5 MB
  char* w = (char*)d_ws;
  size_t off = 0;
  short*    eb = (short*)(w + off);    off += (size_t)NC * ND * 2;
  _Float16* eh = (_Float16*)(w + off); off += (size_t)NC * ND * 2;
  _Float16* el = (_Float16*)(w + off); off += (size_t)NC * ND * 2;
  float*    e2 = (float*)(w + off);    off += (size_t)NC * 4;
  short*    xb = (short*)(w + off);    off += (size_t)NTOK * ND * 2;
  float*  tMin = (float*)(w + off);    off += (size_t)NTOK * NCT * 4;
  int*    list = (int*)(w + off);      off += (size_t)NCT * NTOK * 4;
  int*     cnt = (int*)(w + off);      off += 256;
  unsigned long long* pKey = (unsigned long long*)(w + off); off += (size_t)NTOK * 8;

  prep_embed<<<1024, 256, 0, stream>>>(embed, eb, eh, el);
  prep_e2<<<NC / 4, 256, 0, stream>>>(embed, e2);
  prep_xb<<<2048, 256, 0, stream>>>(x, xb);
  vq_init<<<NTOK / 256, 256, 0, stream>>>(pKey, cnt);
  vq_approx<<<NTT * NCT, 256, 0, stream>>>(xb, lenp, eb, e2, tMin);
  vq_select<<<NTOK / 4, 256, 0, stream>>>(lenp, tMin, list, cnt);
  vq_rescore<<<dim3(NCT, SEGY), 256, 0, stream>>>(x, eh, el, e2, list, cnt, pKey);
  vq_output<<<NTOK / 4, 256, 0, stream>>>(embed, lenp, pKey, out);
}

// Round 3
// 457.824 us; speedup vs baseline: 1.3446x; 1.1524x over previous
//
#include <hip/hip_runtime.h>
#include <cfloat>

typedef _Float16 half8  __attribute__((ext_vector_type(8)));
typedef short    bf16x8 __attribute__((ext_vector_type(8)));
typedef float    floatx4 __attribute__((ext_vector_type(4)));
typedef int      intx4  __attribute__((ext_vector_type(4)));
typedef unsigned long long ull;

#define NBATCH 16
#define NSEQ   2048
#define ND     512
#define NC     8192
#define NTOK   (NBATCH * NSEQ)   // 32768
#define NTT    (NTOK / 128)      // 256 token tiles
#define NCT    (NC / 128)        // 64 code tiles
#define KQ     (ND / 64)         // 8 int8 K-steps (K=64 per MFMA)
#define SEGY   8                 // rescore segment stride
// int8 approx: score err sigma ~0.033 (worst-row absmax~4.9); 0.35 = ~10 sigma.
// Tile-exclusion needs eps(c*) + max_c(-eps) > MARGIN: ~6 sigma event -> safe.
#define MARGIN 0.35f

#define XSCALE 8.0f
#define ESCALE 64.0f
// exact rescore: acc = sum((8x)*(64e)) = 512*xy ; score = e2 - acc/256
#define SCORE_SCALE (2.0f / (XSCALE * ESCALE)) // 1/256

typedef const void __attribute__((address_space(1)))* gp_t;
typedef void       __attribute__((address_space(3)))* lp_t;
__device__ __forceinline__ void cp16(lp_t l, gp_t g) {
  // async global->LDS DMA, 16B/lane, LDS dst = wave-uniform base + lane*16
  __builtin_amdgcn_global_load_lds(g, l, 16, 0, 0);
}

// ---------------- prep: embed -> i8 qe + se + f16 split eh/el + e2 ----------------
// one wave per code row: absmax + sum reduce in-wave, quantize, write 8 B/lane
__global__ __launch_bounds__(256) void prep_embed(const float* __restrict__ embed,
                                                  char* __restrict__ qe,
                                                  float* __restrict__ se,
                                                  _Float16* __restrict__ eh,
                                                  _Float16* __restrict__ el,
                                                  float* __restrict__ e2) {
  int wave = threadIdx.x >> 6, lane = threadIdx.x & 63;
  int c = blockIdx.x * 4 + wave;
  const float* row = embed + (size_t)c * ND;
  float4 v0 = ((const float4*)row)[lane * 2];
  float4 v1 = ((const float4*)row)[lane * 2 + 1];
  float vs[8] = {v0.x, v0.y, v0.z, v0.w, v1.x, v1.y, v1.z, v1.w};
  float am = 0.f, s = 0.f;
#pragma unroll
  for (int q = 0; q < 8; ++q) { am = fmaxf(am, fabsf(vs[q])); s = fmaf(vs[q], vs[q], s); }
#pragma unroll
  for (int m = 1; m < 64; m <<= 1) {
    am = fmaxf(am, __shfl_xor(am, m, 64));
    s += __shfl_xor(s, m, 64);
  }
  float inv = am > 0.f ? 127.f / am : 0.f;
  ull pk = 0; half8 h, l;
#pragma unroll
  for (int q = 0; q < 8; ++q) {
    int qv = (int)rintf(vs[q] * inv);
    qv = min(127, max(-127, qv));
    pk |= (ull)(unsigned char)(signed char)qv << (8 * q);
    float sv = ESCALE * vs[q];
    _Float16 hh = (_Float16)sv;
    h[q] = hh;
    l[q] = (_Float16)(sv - (float)hh);
  }
  ((ull*)(qe + (size_t)c * ND))[lane] = pk;
  ((half8*)(eh + (size_t)c * ND))[lane] = h;
  ((half8*)(el + (size_t)c * ND))[lane] = l;
  if (lane == 0) { se[c] = am / 127.f; e2[c] = s; }
}

// ---------------- prep: x -> i8 qx + sx ----------------
__global__ __launch_bounds__(256) void prep_xq(const float* __restrict__ x,
                                               char* __restrict__ qx,
                                               float* __restrict__ sx) {
  int wave = threadIdx.x >> 6, lane = threadIdx.x & 63;
  int t = blockIdx.x * 4 + wave;
  const float* row = x + (size_t)t * ND;
  float4 v0 = ((const float4*)row)[lane * 2];
  float4 v1 = ((const float4*)row)[lane * 2 + 1];
  float vs[8] = {v0.x, v0.y, v0.z, v0.w, v1.x, v1.y, v1.z, v1.w};
  float am = 0.f;
#pragma unroll
  for (int q = 0; q < 8; ++q) am = fmaxf(am, fabsf(vs[q]));
#pragma unroll
  for (int m = 1; m < 64; m <<= 1) am = fmaxf(am, __shfl_xor(am, m, 64));
  float inv = am > 0.f ? 127.f / am : 0.f;
  ull pk = 0;
#pragma unroll
  for (int q = 0; q < 8; ++q) {
    int qv = (int)rintf(vs[q] * inv);
    qv = min(127, max(-127, qv));
    pk |= (ull)(unsigned char)(signed char)qv << (8 * q);
  }
  ((ull*)(qx + (size_t)t * ND))[lane] = pk;
  if (lane == 0) sx[t] = am / 127.f;
}

// ---------------- init keys + counters ----------------
__global__ __launch_bounds__(256) void vq_init(unsigned long long* __restrict__ pKey,
                                               int* __restrict__ cnt) {
  int i = blockIdx.x * 256 + threadIdx.x;
  pKey[i] = ~0ULL;
  if (i < NCT) cnt[i] = 0;
}

// ---------------- pass 1: i8 GEMM -> per-(token, code-tile) min ----------------
// R9: R8's proven 128x128 tile / 3-deep ring / counted vmcnt, ported to int8
// mfma_i32_16x16x64_i8 (2x bf16 rate, K=64): KSTEPS 16 -> 8, staging bytes
// halve. Byte-layout identical to the bf16 version (rows are still 64 B with
// 16-B granules), so the XOR swizzle / DMA pattern / conflict-free ds_read
// carry over unchanged. Score = e2 - 2*sx*se*acc (per-row scales factor out).
__global__ __launch_bounds__(256) void vq_approx(
    const char* __restrict__ qx, const float* __restrict__ sx,
    const int* __restrict__ len,
    const char* __restrict__ qe, const float* __restrict__ se,
    const float* __restrict__ e2g,
    float* __restrict__ tMin) {
  __shared__ char sXb[3][128 * 64];   // 3 x 8 KiB ring
  __shared__ char sEb[3][128 * 64];   // 3 x 8 KiB ring

  // 8x64 super-tiles: 512 consecutive blocks share 8 X-tiles (L2) + full qe
  const int gid = blockIdx.x;
  const int tt = (gid >> 9) * 8 + (gid & 7);
  const int ct = (gid & 511) >> 3;
  const int b = tt >> 4, s0 = (tt & 15) * 128;
  if (s0 >= len[b]) return;
  const int row0 = tt * 128, code0 = ct * 128;

  const int tid = threadIdx.x, wave = tid >> 6, lane = tid & 63;
  const int quad = lane >> 4, lid = lane & 15;
  const int wr = wave >> 1, wc = wave & 1;

  const int r0 = tid >> 2;
  const int csrc = (tid & 3) ^ ((tid >> 3) & 3);
  const int ldsb0 = wave * 1024;          // byte offsets
  const int ldsb1 = 4096 + wave * 1024;

  const int cswz = quad ^ ((lid >> 1) & 3);
  int aoff[4], boff[4];
#pragma unroll
  for (int i = 0; i < 4; ++i) aoff[i] = (wr * 64 + i * 16 + lid) * 64 + cswz * 16;
#pragma unroll
  for (int j = 0; j < 4; ++j) boff[j] = (wc * 64 + j * 16 + lid) * 64 + cswz * 16;

  const char* pxb = qx + (size_t)(row0 + r0) * ND + csrc * 16;
  const char* peb = qe + (size_t)(code0 + r0) * ND + csrc * 16;

  intx4 acc[4][4];
#pragma unroll
  for (int i = 0; i < 4; ++i)
#pragma unroll
    for (int j = 0; j < 4; ++j) acc[i][j] = (intx4){0, 0, 0, 0};

  // 4 VMEM issues per tile per wave (8 KiB X + 8 KiB E per kt, block-wide 16)
#define STAGE(bufi, kt) do { \
    cp16((lp_t)&sXb[bufi][ldsb0], (gp_t)(pxb + (kt) * 64)); \
    cp16((lp_t)&sXb[bufi][ldsb1], (gp_t)(pxb + 64 * ND + (kt) * 64)); \
    cp16((lp_t)&sEb[bufi][ldsb0], (gp_t)(peb + (kt) * 64)); \
    cp16((lp_t)&sEb[bufi][ldsb1], (gp_t)(peb + 64 * ND + (kt) * 64)); } while (0)

  // prologue: stage tiles 0,1 (8 issues); land tile 0, keep tile 1 in flight
  STAGE(0, 0);
  STAGE(1, 1);
  asm volatile("s_waitcnt vmcnt(4)" ::: "memory");
  __builtin_amdgcn_s_barrier();

#pragma unroll
  for (int kt = 0; kt < KQ; ++kt) {
    const int buf = kt % 3;
    // stage kt+2 into the buffer read at kt-1 (freed by the kt-1 barrier)
    if (kt + 2 < KQ) STAGE((kt + 2) % 3, kt + 2);
    const char* A = sXb[buf];
    const char* B = sEb[buf];
    intx4 av[4], bv[4];
#pragma unroll
    for (int j = 0; j < 4; ++j) bv[j] = *(const intx4*)&B[boff[j]];
#pragma unroll
    for (int i = 0; i < 4; ++i) av[i] = *(const intx4*)&A[aoff[i]];
    __builtin_amdgcn_s_setprio(1);
#pragma unroll
    for (int i = 0; i < 4; ++i)
#pragma unroll
      for (int j = 0; j < 4; ++j)
        acc[i][j] = __builtin_amdgcn_mfma_i32_16x16x64_i8(av[i], bv[j], acc[i][j], 0, 0, 0);
    __builtin_amdgcn_s_setprio(0);
    // boundary: counted wait -- tile kt+1 landed, tile kt+2 stays in flight
    if (kt < KQ - 1) {
      if (kt <= KQ - 3) { asm volatile("s_waitcnt vmcnt(4)" ::: "memory"); }
      else              { asm volatile("s_waitcnt vmcnt(0)" ::: "memory"); }
      __builtin_amdgcn_s_barrier();
    }
  }
#undef STAGE

  // per-token min over this 128-code tile: score = e2 - 2*sx*se*acc
  float e2v[4], sev[4];
#pragma unroll
  for (int j = 0; j < 4; ++j) {
    int col = code0 + wc * 64 + j * 16 + lid;
    e2v[j] = e2g[col];
    sev[j] = se[col];
  }

  __syncthreads();                  // all waves done with LDS -> alias scratch
  float* sc = (float*)&sXb[0][0];   // [128][2]
#pragma unroll
  for (int i = 0; i < 4; ++i) {
#pragma unroll
    for (int reg = 0; reg < 4; ++reg) {
      int row = wr * 64 + i * 16 + quad * 4 + reg;   // C/D row = quad*4+reg
      float rs = 2.0f * sx[row0 + row];
      float best = fmaf(-rs * sev[0], (float)acc[i][0][reg], e2v[0]);
#pragma unroll
      for (int j = 1; j < 4; ++j)
        best = fminf(best, fmaf(-rs * sev[j], (float)acc[i][j][reg], e2v[j]));
#pragma unroll
      for (int m = 1; m < 16; m <<= 1) best = fminf(best, __shfl_xor(best, m, 64));
      if (lid == 0) sc[row * 2 + wc] = best;
    }
  }
  __syncthreads();
  if (tid < 128)
    tMin[(size_t)(row0 + tid) * NCT + ct] = fminf(sc[tid * 2], sc[tid * 2 + 1]);
}

// ---------------- pass 2: select candidate tiles per token ----------------
__global__ __launch_bounds__(256) void vq_select(
    const int* __restrict__ len, const float* __restrict__ tMin,
    int* __restrict__ list, int* __restrict__ cnt) {
  int wave = threadIdx.x >> 6, lane = threadIdx.x & 63;
  int t = blockIdx.x * 4 + wave;
  int b = t >> 11, s = t & (NSEQ - 1);
  if (s >= len[b]) return;   // wave-uniform
  float v = tMin[(size_t)t * NCT + lane];
  float m = v;
#pragma unroll
  for (int d = 1; d < 64; d <<= 1) m = fminf(m, __shfl_xor(m, d, 64));
  if (v <= m + MARGIN) {
    int pos = atomicAdd(&cnt[lane], 1);
    list[lane * NTOK + pos] = t;
  }
}

// ---------------- pass 3: exact 3-product f16 rescore (barrier-free, pipelined) ----
// One block per (code tile j, segment y). Each wave computes a 64x64 quadrant;
// A rows (gathered tokens) and B rows (codes) load global->register; kt loop
// unrolled x2 with ALL 32 loads of the pair issued before convert/MFMA: one
// memory latency per 2 kt instead of a serial per-load chain (blocks run at
// ~1 wave/SIMD, so intra-wave ILP is the only latency hiding available).
// atomicMin on sortable (score,idx) u64 key: order-independent, idempotent.
__global__ __launch_bounds__(256, 1) void vq_rescore(
    const float* __restrict__ x,
    const _Float16* __restrict__ eh, const _Float16* __restrict__ el,
    const float* __restrict__ e2g,
    const int* __restrict__ list, const int* __restrict__ cnt,
    unsigned long long* __restrict__ pKey) {
  const int j = blockIdx.x;
  const int n = cnt[j];
  const int code0 = j * 128;

  const int tid = threadIdx.x, wave = tid >> 6, lane = tid & 63;
  const int quad = lane >> 4, lid = lane & 15;
  const int wr = wave >> 1, wc = wave & 1;

  float e2v[4]; int cjv[4];
#pragma unroll
  for (int jj = 0; jj < 4; ++jj) {
    cjv[jj] = code0 + wc * 64 + jj * 16 + lid;   // B row = C/D col = lane&15
    e2v[jj] = e2g[cjv[jj]];
  }

  for (int seg = blockIdx.y; seg * 128 < n; seg += SEGY) {
    const int base = seg * 128;
    int tok[4];
#pragma unroll
    for (int i = 0; i < 4; ++i)
      tok[i] = list[j * NTOK + min(base + wr * 64 + i * 16 + lid, n - 1)];

    floatx4 acc[4][4];
#pragma unroll
    for (int i = 0; i < 4; ++i)
#pragma unroll
      for (int jj = 0; jj < 4; ++jj) acc[i][jj] = (floatx4){0.f, 0.f, 0.f, 0.f};

    for (int kt = 0; kt < 16; kt += 2) {
      // ---- issue ALL loads for the kt pair (32 instrs in flight) ----
      float4 af[2][4][2];
#pragma unroll
      for (int s = 0; s < 2; ++s)
#pragma unroll
        for (int i = 0; i < 4; ++i) {
          const float* px = x + (size_t)tok[i] * ND + (kt + s) * 32 + quad * 8;
          af[s][i][0] = *(const float4*)px;
          af[s][i][1] = *(const float4*)(px + 4);
        }
      half8 bh[2][4], bl[2][4];
#pragma unroll
      for (int s = 0; s < 2; ++s)
#pragma unroll
        for (int jj = 0; jj < 4; ++jj) {
          const size_t eo = (size_t)cjv[jj] * ND + (kt + s) * 32 + quad * 8;
          bh[s][jj] = *(const half8*)(eh + eo);
          bl[s][jj] = *(const half8*)(el + eo);
        }
      // ---- process sub-steps in order (same arithmetic order as R5/R6) ----
#pragma unroll
      for (int s = 0; s < 2; ++s) {
        half8 ah[4], al[4];
#pragma unroll
        for (int i = 0; i < 4; ++i) {
          float vs[8] = {af[s][i][0].x, af[s][i][0].y, af[s][i][0].z, af[s][i][0].w,
                         af[s][i][1].x, af[s][i][1].y, af[s][i][1].z, af[s][i][1].w};
#pragma unroll
          for (int q = 0; q < 8; ++q) {
            float vv = XSCALE * vs[q];
            _Float16 hh = (_Float16)vv;
            ah[i][q] = hh;
            al[i][q] = (_Float16)(vv - (float)hh);
          }
        }
#pragma unroll
        for (int i = 0; i < 4; ++i)
#pragma unroll
          for (int jj = 0; jj < 4; ++jj) {
            acc[i][jj] = __builtin_amdgcn_mfma_f32_16x16x32_f16(ah[i], bh[s][jj], acc[i][jj], 0, 0, 0);
            acc[i][jj] = __builtin_amdgcn_mfma_f32_16x16x32_f16(ah[i], bl[s][jj], acc[i][jj], 0, 0, 0);
            acc[i][jj] = __builtin_amdgcn_mfma_f32_16x16x32_f16(al[i], bh[s][jj], acc[i][jj], 0, 0, 0);
          }
      }
    }

    // epilogue: per-row argmin over the 128 codes, publish via atomicMin
#pragma unroll
    for (int i = 0; i < 4; ++i) {
#pragma unroll
      for (int reg = 0; reg < 4; ++reg) {
        float best = fmaf(-SCORE_SCALE, acc[i][0][reg], e2v[0]);
        int bidx = cjv[0];
#pragma unroll
        for (int jj = 1; jj < 4; ++jj) {
          float vj = fmaf(-SCORE_SCALE, acc[i][jj][reg], e2v[jj]);
          if (vj < best) { best = vj; bidx = cjv[jj]; }   // strict <: lowest idx on ties
        }
#pragma unroll
        for (int m = 1; m < 16; m <<= 1) {
          float ov = __shfl_xor(best, m, 64);
          int   oi = __shfl_xor(bidx, m, 64);
          if (ov < best || (ov == best && oi < bidx)) { best = ov; bidx = oi; }
        }
        if (lid == 0) {
          int row = wr * 64 + i * 16 + quad * 4 + reg;    // C/D row = quad*4+reg
          int t = list[j * NTOK + min(base + row, n - 1)];
          if (best == 0.0f) best = 0.0f;                  // normalize -0
          unsigned u = __float_as_uint(best);
          u ^= (u >> 31) ? 0xFFFFFFFFu : 0x80000000u;     // sortable fp32
          unsigned long long key = ((unsigned long long)u << 32) | (unsigned)bidx;
          atomicMin(&pKey[t], key);
        }
      }
    }
  }
}

// ---------------- decode key, gather code row, apply mask ----------------
__global__ __launch_bounds__(256) void vq_output(
    const float* __restrict__ embed, const int* __restrict__ len,
    const unsigned long long* __restrict__ pKey,
    float* __restrict__ out) {
  int wave = threadIdx.x >> 6, lane = threadIdx.x & 63;
  int t = blockIdx.x * 4 + wave;
  int b = t >> 11, s = t & (NSEQ - 1);
  float* outq = out + (size_t)t * ND;
  float* outind = out + (size_t)NTOK * ND;
  if (s >= len[b]) {
    float4 z = {0.f, 0.f, 0.f, 0.f};
    *(float4*)&outq[lane * 8]     = z;
    *(float4*)&outq[lane * 8 + 4] = z;
    if (lane == 0) outind[t] = -1.0f;
    return;
  }
  unsigned long long key = pKey[t];
  int bi = (int)(unsigned)(key & 0xFFFFFFFFULL);
  const float* er = embed + (size_t)bi * ND;
  *(float4*)&outq[lane * 8]     = *(const float4*)&er[lane * 8];
  *(float4*)&outq[lane * 8 + 4] = *(const float4*)&er[lane * 8 + 4];
  if (lane == 0) outind[t] = (float)bi;
}

extern "C" void kernel_launch(void* const* d_in, const int* in_sizes, int n_in,
                              void* d_out, int out_size, void* d_ws, size_t ws_size,
                              hipStream_t stream) {
  const float* x     = (const float*)d_in[0];
  const int*   lenp  = (const int*)d_in[1];
  const float* embed = (const float*)d_in[2];
  float* out = (float*)d_out;

  // ws: qe 4M | se 32K | eh 8M | el 8M | e2 32K | qx 16M | sx 128K |
  //     tMin 8M | list 8M | cnt | pKey 256K   ~52.5 MB
  char* w = (char*)d_ws;
  size_t off = 0;
  char*     qe = (char*)(w + off);     off += (size_t)NC * ND;
  float*    se = (float*)(w + off);    off += (size_t)NC * 4;
  _Float16* eh = (_Float16*)(w + off); off += (size_t)NC * ND * 2;
  _Float16* el = (_Float16*)(w + off); off += (size_t)NC * ND * 2;
  float*    e2 = (float*)(w + off);    off += (size_t)NC * 4;
  char*     qx = (char*)(w + off);     off += (size_t)NTOK * ND;
  float*    sx = (float*)(w + off);    off += (size_t)NTOK * 4;
  float*  tMin = (float*)(w + off);    off += (size_t)NTOK * NCT * 4;
  int*    list = (int*)(w + off);      off += (size_t)NCT * NTOK * 4;
  int*     cnt = (int*)(w + off);      off += 256;
  unsigned long long* pKey = (unsigned long long*)(w + off); off += (size_t)NTOK * 8;

  prep_embed<<<NC / 4, 256, 0, stream>>>(embed, qe, se, eh, el, e2);
  prep_xq<<<NTOK / 4, 256, 0, stream>>>(x, qx, sx);
  vq_init<<<NTOK / 256, 256, 0, stream>>>(pKey, cnt);
  vq_approx<<<NTT * NCT, 256, 0, stream>>>(qx, sx, lenp, qe, se, e2, tMin);
  vq_select<<<NTOK / 4, 256, 0, stream>>>(lenp, tMin, list, cnt);
  vq_rescore<<<dim3(NCT, SEGY), 256, 0, stream>>>(x, eh, el, e2, list, cnt, pKey);
  vq_output<<<NTOK / 4, 256, 0, stream>>>(embed, lenp, pKey, out);
}